// Round 11
// baseline (415.575 us; speedup 1.0000x reference)
//
#include <hip/hip_runtime.h>
#include <hip/hip_bf16.h>

// B=8, L=4096, C=384, h=8, d=48, H=W=64
// Algebraic restructure: G = k^T v = Wk (X^T X) Wv^T (+bias terms); y = q@A2
// = X (Wq^T A2) -> per-batch folded weight. q,k never materialized at length L.
// S kept to fp32 precision via bf16 hi+lo split for the T = Wqk*S GEMM.
// R10 bug fixed: S2 properly sized (4,718,592 B); m/weights moved past it.

typedef __bf16 bf16x8 __attribute__((ext_vector_type(8)));
typedef float f32x4 __attribute__((ext_vector_type(4)));

__device__ inline __bf16 f2b(float f) {
    __hip_bfloat16 h = __float2bfloat16(f);
    __bf16 r; __builtin_memcpy(&r, &h, 2); return r;
}
__device__ inline float b2f(__hip_bfloat16 h) { return __bfloat162float(h); }
__device__ inline float b2f(__bf16 v) {
    __hip_bfloat16 h; __builtin_memcpy(&h, &v, 2); return __bfloat162float(h);
}

__device__ inline bf16x8 load8(const __hip_bfloat16* p) {
    uint4 v = *(const uint4*)p;
    bf16x8 r; __builtin_memcpy(&r, &v, 16); return r;
}
__device__ inline bf16x8 load8(const float* p) {
    float4 a = *(const float4*)p;
    float4 b = *(const float4*)(p + 4);
    bf16x8 r;
    r[0] = f2b(a.x); r[1] = f2b(a.y); r[2] = f2b(a.z); r[3] = f2b(a.w);
    r[4] = f2b(b.x); r[5] = f2b(b.y); r[6] = f2b(b.z); r[7] = f2b(b.w);
    return r;
}

__device__ inline void storef(float* p, float v) { *p = v; }
__device__ inline void storef(__hip_bfloat16* p, float v) { *p = __float2bfloat16(v); }

// async 16B global -> LDS (wave-uniform base + lane*16 dest required)
__device__ inline void gl_lds16(const __hip_bfloat16* g, __hip_bfloat16* l) {
    __builtin_amdgcn_global_load_lds(
        (const __attribute__((address_space(1))) void*)g,
        (__attribute__((address_space(3))) void*)l,
        16, 0, 0);
}

// ---------------------------------------------------------------------------
// fp32 -> bf16: x (6144 blocks), qkv_w (216), proj_w (72); blocks >= 6432
// zero the m accumulator (768 uint4 = 3 blocks).
// ---------------------------------------------------------------------------
__global__ __launch_bounds__(256) void cvt_kernel(
    const float* __restrict__ x,  __hip_bfloat16* __restrict__ xb,
    const float* __restrict__ qw, __hip_bfloat16* __restrict__ qwb,
    const float* __restrict__ pw, __hip_bfloat16* __restrict__ pwb,
    uint4* __restrict__ zdst)
{
    int blk = blockIdx.x;
    if (blk >= 6432) {   // 3 blocks: zero m (12288 B)
        zdst[(size_t)(blk - 6432) * 256 + threadIdx.x] = (uint4){0, 0, 0, 0};
        return;
    }
    const float* src; __hip_bfloat16* dst; int base;
    if (blk < 6144)      { src = x;  dst = xb;  base = blk; }
    else if (blk < 6360) { src = qw; dst = qwb; base = blk - 6144; }
    else                 { src = pw; dst = pwb; base = blk - 6360; }
    int i = base * 256 + threadIdx.x;
    bf16x8 v = load8(src + (size_t)i * 8);
    *(bf16x8*)(dst + (size_t)i * 8) = v;
}

// ---------------------------------------------------------------------------
// Transpose X (bf16 [B,4096,384]) -> xT (bf16 [B,384,4096]); also m = X^T 1
// (fp32, atomicAdd, zeroed in cvt). Grid (64 l-tiles, 6 c-tiles, 8 b).
// ---------------------------------------------------------------------------
__global__ __launch_bounds__(256) void xpose_kernel(
    const __hip_bfloat16* __restrict__ xb, __hip_bfloat16* __restrict__ xT,
    float* __restrict__ m)
{
    __shared__ __hip_bfloat16 tile[64][72];   // 144B row stride (odd x16)
    const int lt = blockIdx.x, ct = blockIdx.y, b = blockIdx.z;
    const int l0 = lt * 64, c0 = ct * 64;
    const int t = threadIdx.x;

    // load 64x64 tile: 512 chunks of 8 cols
    #pragma unroll
    for (int p = 0; p < 2; ++p) {
        int cid = t + p * 256;
        int row = cid >> 3, ch = cid & 7;
        *(bf16x8*)&tile[row][ch * 8] =
            load8(xb + (size_t)(b * 4096 + l0 + row) * 384 + c0 + ch * 8);
    }
    __syncthreads();

    // write transposed: 512 out-chunks; chunk (c, lch) -> xT[c0+c][l0+lch*8..]
    #pragma unroll
    for (int p = 0; p < 2; ++p) {
        int ocid = t + p * 256;
        int c = ocid >> 3, lch = ocid & 7;
        __hip_bfloat16 vals[8];
        #pragma unroll
        for (int k = 0; k < 8; ++k) {
            int j = (k + lch) & 7;          // rotated order: breaks bank lockstep
            vals[j] = tile[lch * 8 + j][c];
        }
        bf16x8 pk;
        float s = 0.f;
        #pragma unroll
        for (int j = 0; j < 8; ++j) { pk[j] = *(__bf16*)&vals[j]; s += b2f(vals[j]); }
        *(bf16x8*)(xT + ((size_t)b * 384 + c0 + c) * 4096 + l0 + lch * 8) = pk;
        // column-sum reduce over the 8-lane lch group
        s += __shfl_xor(s, 1); s += __shfl_xor(s, 2); s += __shfl_xor(s, 4);
        if ((ocid & 7) == 0) atomicAdd(&m[b * 384 + c0 + c], s);
    }
}

// ---------------------------------------------------------------------------
// S partials: Spart[split][b][384][384] (fp32, plain stores) = X^T X over
// l in [split*1024, +1024). Grid 576 = 8b x 18 tiles(3x6) x 4 splits.
// K-loop identical to the verified gemm skeleton (A = B = xT[b]).
// ---------------------------------------------------------------------------
__global__ __launch_bounds__(256) void syrk_part(
    const __hip_bfloat16* __restrict__ xT, float* __restrict__ Spart)
{
    __shared__ __hip_bfloat16 As[128 * 64];
    __shared__ __hip_bfloat16 Bs[64 * 64];
    const int t = threadIdx.x;
    const int w = t >> 6, lane = t & 63;
    const int r16 = lane & 15, quad = lane >> 4;
    const int bx = blockIdx.x;
    const int b = bx / 72, rem = bx % 72;
    const int tile = rem / 4, split = rem % 4;
    const int m0 = (tile / 6) * 128, n0 = (tile % 6) * 64;
    const int k_lo = split * 1024;
    const int wm = w >> 1, wn = w & 1;
    const __hip_bfloat16* A = xT + (size_t)b * 384 * 4096;

    f32x4 acc[4][2];
    #pragma unroll
    for (int mi = 0; mi < 4; ++mi)
        #pragma unroll
        for (int ni = 0; ni < 2; ++ni)
            acc[mi][ni] = (f32x4){0.f, 0.f, 0.f, 0.f};

    for (int it = 0; it < 16; ++it) {
        const int k0 = k_lo + it * 64;
        #pragma unroll
        for (int p = 0; p < 4; ++p) {
            int c = p * 64 + lane;
            int rl = c >> 3;
            int cc = (c & 7) ^ (rl & 7);
            gl_lds16(A + (size_t)(m0 + w * 32 + rl) * 4096 + k0 + cc * 8,
                     &As[(w * 256 + c) * 8]);
        }
        #pragma unroll
        for (int p = 0; p < 2; ++p) {
            int c = p * 64 + lane;
            int rl = c >> 3;
            int cc = (c & 7) ^ (rl & 7);
            gl_lds16(A + (size_t)(n0 + w * 16 + rl) * 4096 + k0 + cc * 8,
                     &Bs[(w * 128 + c) * 8]);
        }
        __syncthreads();
        bf16x8 af[4][2], bfr[2][2];
        #pragma unroll
        for (int ks = 0; ks < 2; ++ks) {
            #pragma unroll
            for (int mi = 0; mi < 4; ++mi) {
                int row = wm * 64 + mi * 16 + r16;
                int pc  = (ks * 4 + quad) ^ (r16 & 7);
                af[mi][ks] = *(const bf16x8*)&As[row * 64 + pc * 8];
            }
            #pragma unroll
            for (int ni = 0; ni < 2; ++ni) {
                int row = wn * 32 + ni * 16 + r16;
                int pc  = (ks * 4 + quad) ^ (r16 & 7);
                bfr[ni][ks] = *(const bf16x8*)&Bs[row * 64 + pc * 8];
            }
        }
        #pragma unroll
        for (int ks = 0; ks < 2; ++ks)
            #pragma unroll
            for (int mi = 0; mi < 4; ++mi)
                #pragma unroll
                for (int ni = 0; ni < 2; ++ni)
                    acc[mi][ni] = __builtin_amdgcn_mfma_f32_16x16x32_bf16(
                        af[mi][ks], bfr[ni][ks], acc[mi][ni], 0, 0, 0);
        __syncthreads();
    }

    float* outp = Spart + (size_t)(split * 8 + b) * 147456;
    #pragma unroll
    for (int ni = 0; ni < 2; ++ni) {
        int col = n0 + wn * 32 + ni * 16 + r16;
        #pragma unroll
        for (int mi = 0; mi < 4; ++mi)
            #pragma unroll
            for (int reg = 0; reg < 4; ++reg) {
                int row = m0 + wm * 64 + mi * 16 + quad * 4 + reg;
                outp[(size_t)row * 384 + col] = acc[mi][ni][reg];
            }
    }
}

// ---------------------------------------------------------------------------
// Sum the 4 split partials -> S (fp32), emit bf16 hi/lo pair S2[b][2][384*384].
// ---------------------------------------------------------------------------
__global__ __launch_bounds__(256) void cvtS_kernel(
    const float* __restrict__ Spart, __hip_bfloat16* __restrict__ S2)
{
    size_t base = ((size_t)blockIdx.x * 256 + threadIdx.x) * 8;
    int b = (int)(base / 147456);
    size_t off = base % 147456;
    float s[8];
    #pragma unroll
    for (int j = 0; j < 8; ++j) s[j] = 0.f;
    #pragma unroll
    for (int sp = 0; sp < 4; ++sp) {
        const float* p = Spart + (size_t)(sp * 8 + b) * 147456 + off;
        float4 a = *(const float4*)p, c = *(const float4*)(p + 4);
        s[0] += a.x; s[1] += a.y; s[2] += a.z; s[3] += a.w;
        s[4] += c.x; s[5] += c.y; s[6] += c.z; s[7] += c.w;
    }
    bf16x8 hi, lo;
    #pragma unroll
    for (int j = 0; j < 8; ++j) {
        __hip_bfloat16 h = __float2bfloat16(s[j]);
        hi[j] = *(__bf16*)&h;
        __hip_bfloat16 l2 = __float2bfloat16(s[j] - __bfloat162float(h));
        lo[j] = *(__bf16*)&l2;
    }
    *(bf16x8*)(S2 + (size_t)(b * 2 + 0) * 147456 + off) = hi;
    *(bf16x8*)(S2 + (size_t)(b * 2 + 1) * 147456 + off) = lo;
}

// ---------------------------------------------------------------------------
// T[b] = Wqk (768x384) @ S[b] (sym) : two bf16 passes (S_hi, S_lo) accumulate
// fp32-S precision. Grid 288 = 8b x 6 row-tiles x 6 col-tiles. fp32 out.
// ---------------------------------------------------------------------------
__global__ __launch_bounds__(256) void gemm_T(
    const __hip_bfloat16* __restrict__ Wqk, const __hip_bfloat16* __restrict__ S2,
    float* __restrict__ T)
{
    __shared__ __hip_bfloat16 As[128 * 64];
    __shared__ __hip_bfloat16 Bs[64 * 64];
    const int t = threadIdx.x;
    const int w = t >> 6, lane = t & 63;
    const int r16 = lane & 15, quad = lane >> 4;
    const int bx = blockIdx.x;
    const int b = bx / 36, rem = bx % 36;
    const int m0 = (rem / 6) * 128, n0 = (rem % 6) * 64;
    const int wm = w >> 1, wn = w & 1;

    f32x4 acc[4][2];
    #pragma unroll
    for (int mi = 0; mi < 4; ++mi)
        #pragma unroll
        for (int ni = 0; ni < 2; ++ni)
            acc[mi][ni] = (f32x4){0.f, 0.f, 0.f, 0.f};

    for (int pass = 0; pass < 2; ++pass) {
        const __hip_bfloat16* Bw = S2 + (size_t)(b * 2 + pass) * 147456;
        for (int k0 = 0; k0 < 384; k0 += 64) {
            #pragma unroll
            for (int p = 0; p < 4; ++p) {
                int c = p * 64 + lane;
                int rl = c >> 3;
                int cc = (c & 7) ^ (rl & 7);
                gl_lds16(Wqk + (size_t)(m0 + w * 32 + rl) * 384 + k0 + cc * 8,
                         &As[(w * 256 + c) * 8]);
            }
            #pragma unroll
            for (int p = 0; p < 2; ++p) {
                int c = p * 64 + lane;
                int rl = c >> 3;
                int cc = (c & 7) ^ (rl & 7);
                gl_lds16(Bw + (size_t)(n0 + w * 16 + rl) * 384 + k0 + cc * 8,
                         &Bs[(w * 128 + c) * 8]);
            }
            __syncthreads();
            bf16x8 af[4][2], bfr[2][2];
            #pragma unroll
            for (int ks = 0; ks < 2; ++ks) {
                #pragma unroll
                for (int mi = 0; mi < 4; ++mi) {
                    int row = wm * 64 + mi * 16 + r16;
                    int pc  = (ks * 4 + quad) ^ (r16 & 7);
                    af[mi][ks] = *(const bf16x8*)&As[row * 64 + pc * 8];
                }
                #pragma unroll
                for (int ni = 0; ni < 2; ++ni) {
                    int row = wn * 32 + ni * 16 + r16;
                    int pc  = (ks * 4 + quad) ^ (r16 & 7);
                    bfr[ni][ks] = *(const bf16x8*)&Bs[row * 64 + pc * 8];
                }
            }
            #pragma unroll
            for (int ks = 0; ks < 2; ++ks)
                #pragma unroll
                for (int mi = 0; mi < 4; ++mi)
                    #pragma unroll
                    for (int ni = 0; ni < 2; ++ni)
                        acc[mi][ni] = __builtin_amdgcn_mfma_f32_16x16x32_bf16(
                            af[mi][ks], bfr[ni][ks], acc[mi][ni], 0, 0, 0);
            __syncthreads();
        }
    }

    float* Cp = T + (size_t)b * 768 * 384;
    #pragma unroll
    for (int ni = 0; ni < 2; ++ni) {
        int col = n0 + wn * 32 + ni * 16 + r16;
        #pragma unroll
        for (int mi = 0; mi < 4; ++mi)
            #pragma unroll
            for (int reg = 0; reg < 4; ++reg) {
                int row = m0 + wm * 64 + mi * 16 + quad * 4 + reg;
                Cp[(size_t)row * 384 + col] = acc[mi][ni][reg];
            }
    }
}

// ---------------------------------------------------------------------------
// Per (b,h): G, invnorms, attn_out, A2, W_eff = Wq^T A2 (bf16), b_eff.
// Grid 64 blocks.
//   G[d,e] = sum_j t_k[d,j] Wv[e,j] + kbm[d] bv[e] + bk[d] vbm[e] + L bk bv
//   sumsq_k[d] = sum_j t_k[d,j] Wk[d,j] + 2 bk kbm[d] + L bk^2   (q likewise)
// ---------------------------------------------------------------------------
__global__ __launch_bounds__(256) void head_kernel(
    const float* __restrict__ T, const float* __restrict__ m,
    const __hip_bfloat16* __restrict__ qkvw, const float* __restrict__ qkv_b,
    const float* __restrict__ temp,
    float* __restrict__ attn_out, __hip_bfloat16* __restrict__ weff,
    float* __restrict__ beff)
{
    __shared__ __hip_bfloat16 wlds[48][384];   // Wv then Wq
    __shared__ float A2[48][48];
    __shared__ float ink[48], inq[48], kbm[48], vbm[48], qbm[48];
    __shared__ float bk_s[48], bv_s[48], bq_s[48];

    const int bh = blockIdx.x; const int b = bh >> 3, h = bh & 7;
    const int t = threadIdx.x;
    const float tf = temp[h];
    const float* mb = m + b * 384;
    const float* tq = T + ((size_t)b * 768 + h * 48) * 384;
    const float* tk = T + ((size_t)b * 768 + 384 + h * 48) * 384;

    // stage Wv
    for (int i = t; i < 48 * 48; i += 256) {
        int r = i / 48, c = i % 48;
        *(bf16x8*)&wlds[r][c * 8] = load8(qkvw + (size_t)(768 + h * 48 + r) * 384 + c * 8);
    }
    if (t < 48) {
        bq_s[t] = qkv_b[h * 48 + t];
        bk_s[t] = qkv_b[384 + h * 48 + t];
        bv_s[t] = qkv_b[768 + h * 48 + t];
    }
    if (t < 144) {   // m-dots: kind 0=k,1=v,2=q
        int kind = t / 48, d = t % 48;
        int rbase = (kind == 0) ? 384 + h * 48 + d : (kind == 1) ? 768 + h * 48 + d : h * 48 + d;
        const __hip_bfloat16* wr = qkvw + (size_t)rbase * 384;
        float s = 0.f;
        for (int j0 = 0; j0 < 384; j0 += 8) {
            bf16x8 wv = load8(wr + j0);
            const float4 a = *(const float4*)(mb + j0);
            const float4 c = *(const float4*)(mb + j0 + 4);
            s += b2f(wv[0])*a.x + b2f(wv[1])*a.y + b2f(wv[2])*a.z + b2f(wv[3])*a.w
               + b2f(wv[4])*c.x + b2f(wv[5])*c.y + b2f(wv[6])*c.z + b2f(wv[7])*c.w;
        }
        if (kind == 0) kbm[d] = s; else if (kind == 1) vbm[d] = s; else qbm[d] = s;
    }
    __syncthreads();

    if (t < 96) {   // sumsq -> invnorms
        int d = t % 48; bool isq = t >= 48;
        const float* trow = (isq ? tq : tk) + (size_t)d * 384;
        const __hip_bfloat16* wr = qkvw + (size_t)((isq ? 0 : 384) + h * 48 + d) * 384;
        float bb = isq ? bq_s[d] : bk_s[d];
        float s = 0.f;
        for (int j0 = 0; j0 < 384; j0 += 8) {
            bf16x8 wv = load8(wr + j0);
            const float4 a = *(const float4*)(trow + j0);
            const float4 c = *(const float4*)(trow + j0 + 4);
            s += a.x*b2f(wv[0]) + a.y*b2f(wv[1]) + a.z*b2f(wv[2]) + a.w*b2f(wv[3])
               + c.x*b2f(wv[4]) + c.y*b2f(wv[5]) + c.z*b2f(wv[6]) + c.w*b2f(wv[7]);
        }
        s += 2.f * bb * (isq ? qbm[d] : kbm[d]) + 4096.f * bb * bb;
        float r = 1.f / fmaxf(sqrtf(s), 1e-12f);
        if (isq) inq[d] = r; else ink[d] = r;
    }
    __syncthreads();

    // G cells -> attn_out + A2
    #pragma unroll
    for (int kk = 0; kk < 9; ++kk) {
        int cell = t + kk * 256;
        int d = cell / 48, e = cell % 48;
        const float* trow = tk + (size_t)d * 384;
        float g = 0.f;
        for (int j0 = 0; j0 < 384; j0 += 8) {
            bf16x8 wv = *(const bf16x8*)&wlds[e][j0];
            const float4 a = *(const float4*)(trow + j0);
            const float4 c = *(const float4*)(trow + j0 + 4);
            g += a.x*b2f(wv[0]) + a.y*b2f(wv[1]) + a.z*b2f(wv[2]) + a.w*b2f(wv[3])
               + c.x*b2f(wv[4]) + c.y*b2f(wv[5]) + c.z*b2f(wv[6]) + c.w*b2f(wv[7]);
        }
        g += kbm[d] * bv_s[e] + bk_s[d] * vbm[e] + 4096.f * bk_s[d] * bv_s[e];
        float av = g * ink[d] * tf;
        attn_out[(size_t)bh * 2304 + cell] = av;
        A2[d][e] = av * inq[d];
    }
    __syncthreads();

    // restage Wq over wlds
    for (int i = t; i < 48 * 48; i += 256) {
        int r = i / 48, c = i % 48;
        *(bf16x8*)&wlds[r][c * 8] = load8(qkvw + (size_t)(h * 48 + r) * 384 + c * 8);
    }
    if (t < 48) {   // b_eff
        float s = 0.f;
        #pragma unroll
        for (int d2 = 0; d2 < 48; ++d2) s += bq_s[d2] * A2[d2][t];
        beff[(size_t)b * 384 + h * 48 + t] = s;
    }
    __syncthreads();

    // W_eff rows: weff_rm[e, i] = sum_d A2[d,e] Wq[d,i]
    for (int idx = t; idx < 48 * 384; idx += 256) {
        int e = idx / 384, i2 = idx % 384;
        float s = 0.f;
        #pragma unroll
        for (int d2 = 0; d2 < 48; ++d2) s += A2[d2][e] * b2f(wlds[d2][i2]);
        weff[((size_t)b * 384 + h * 48 + e) * 384 + i2] = __float2bfloat16(s);
    }
}

// ---------------------------------------------------------------------------
// vy GEMM: C[32768][768] = [ v | y_pre ]: cols<384 -> Wv rows (shared) +
// qkv_b[768+..]; cols>=384 -> per-batch W_eff rows + b_eff. bf16 out.
// Grid 3072 (XCD swizzle, NXT=12).
// ---------------------------------------------------------------------------
__global__ __launch_bounds__(256) void gemm_vy(
    const __hip_bfloat16* __restrict__ A, const __hip_bfloat16* __restrict__ qkvw,
    const __hip_bfloat16* __restrict__ weff,
    const float* __restrict__ qkv_b, const float* __restrict__ beff,
    __hip_bfloat16* __restrict__ C)
{
    __shared__ __hip_bfloat16 As[128 * 64];
    __shared__ __hip_bfloat16 Bs[64 * 64];
    const int t = threadIdx.x;
    const int w = t >> 6, lane = t & 63;
    const int r16 = lane & 15, quad = lane >> 4;
    const int bx = blockIdx.x;
    const int xcd = bx & 7, seq = bx >> 3;
    const int n_t = seq % 12, m_t = seq / 12;
    const int m0 = (xcd + 8 * m_t) * 128;
    const int n0 = n_t * 64;
    const int b = m0 >> 12;
    const int wm = w >> 1, wn = w & 1;

    f32x4 acc[4][2];
    #pragma unroll
    for (int mi = 0; mi < 4; ++mi)
        #pragma unroll
        for (int ni = 0; ni < 2; ++ni)
            acc[mi][ni] = (f32x4){0.f, 0.f, 0.f, 0.f};

    for (int k0 = 0; k0 < 384; k0 += 64) {
        #pragma unroll
        for (int p = 0; p < 4; ++p) {
            int c = p * 64 + lane;
            int rl = c >> 3;
            int cc = (c & 7) ^ (rl & 7);
            gl_lds16(A + (size_t)(m0 + w * 32 + rl) * 384 + k0 + cc * 8,
                     &As[(w * 256 + c) * 8]);
        }
        #pragma unroll
        for (int p = 0; p < 2; ++p) {
            int c = p * 64 + lane;
            int rl = c >> 3;
            int cc = (c & 7) ^ (rl & 7);
            int n = n0 + w * 16 + rl;
            const __hip_bfloat16* brow = (n < 384)
                ? qkvw + (size_t)(768 + n) * 384
                : weff + ((size_t)b * 384 + (n - 384)) * 384;
            gl_lds16(brow + k0 + cc * 8, &Bs[(w * 128 + c) * 8]);
        }
        __syncthreads();
        bf16x8 af[4][2], bfr[2][2];
        #pragma unroll
        for (int ks = 0; ks < 2; ++ks) {
            #pragma unroll
            for (int mi = 0; mi < 4; ++mi) {
                int row = wm * 64 + mi * 16 + r16;
                int pc  = (ks * 4 + quad) ^ (r16 & 7);
                af[mi][ks] = *(const bf16x8*)&As[row * 64 + pc * 8];
            }
            #pragma unroll
            for (int ni = 0; ni < 2; ++ni) {
                int row = wn * 32 + ni * 16 + r16;
                int pc  = (ks * 4 + quad) ^ (r16 & 7);
                bfr[ni][ks] = *(const bf16x8*)&Bs[row * 64 + pc * 8];
            }
        }
        #pragma unroll
        for (int ks = 0; ks < 2; ++ks)
            #pragma unroll
            for (int mi = 0; mi < 4; ++mi)
                #pragma unroll
                for (int ni = 0; ni < 2; ++ni)
                    acc[mi][ni] = __builtin_amdgcn_mfma_f32_16x16x32_bf16(
                        af[mi][ks], bfr[ni][ks], acc[mi][ni], 0, 0, 0);
        __syncthreads();
    }

    #pragma unroll
    for (int ni = 0; ni < 2; ++ni) {
        int col = n0 + wn * 32 + ni * 16 + r16;
        float bv = (col < 384) ? qkv_b[768 + col] : beff[(size_t)b * 384 + col - 384];
        #pragma unroll
        for (int mi = 0; mi < 4; ++mi)
            #pragma unroll
            for (int reg = 0; reg < 4; ++reg) {
                int row = m0 + wm * 64 + mi * 16 + quad * 4 + reg;
                C[(size_t)row * 768 + col] = __float2bfloat16(acc[mi][ni][reg] + bv);
            }
    }
}

// ---------------------------------------------------------------------------
// yb = y_pre + lepe(v): depthwise 3x3 conv on v (image 64x64 per b,c) + bias.
// Grid (32, 64): (2 image rows, bh).
// ---------------------------------------------------------------------------
__global__ __launch_bounds__(256) void lepe_kernel(
    const __hip_bfloat16* __restrict__ vy,
    const float* __restrict__ conv_w, const float* __restrict__ conv_b,
    __hip_bfloat16* __restrict__ y)
{
    __shared__ __hip_bfloat16 vs[4][64][48];   // 24576 B
    __shared__ float cwT[9][48];
    __shared__ float cb[48];

    const int bh = blockIdx.y; const int b = bh >> 3; const int h = bh & 7;
    const int yi0 = blockIdx.x * 2;
    const int l0  = yi0 * 64;
    const int t = threadIdx.x;

    // stage v image rows yi0-1 .. yi0+2 (zeros outside image)
    const __hip_bfloat16* vbase = vy + (size_t)b * 4096 * 768 + h * 48;
    #pragma unroll
    for (int i = 0; i < 6; ++i) {
        int chunk = t + i * 256;               // 1536 chunks
        int r = chunk / 384, rem = chunk % 384;
        int xx = rem / 6, cg = rem % 6;
        int yy = yi0 - 1 + r;
        bf16x8 v = (yy >= 0 && yy < 64)
            ? load8(vbase + (size_t)(yy * 64 + xx) * 768 + cg * 8)
            : (bf16x8)0;
        *(bf16x8*)&vs[r][xx][cg * 8] = v;
    }
    for (int i = t; i < 432; i += 256)
        cwT[i / 48][i % 48] = conv_w[(h * 48 + (i % 48)) * 9 + (i / 48)];
    if (t < 48) cb[t] = conv_b[h * 48 + t];
    __syncthreads();

    const __hip_bfloat16* ybase_in = vy + (size_t)(b * 4096 + l0) * 768 + 384 + h * 48;
    __hip_bfloat16* ybase = y + (size_t)(b * 4096 + l0) * 384 + h * 48;
    #pragma unroll
    for (int i = 0; i < 3; ++i) {
        int g = t + i * 256;                   // 768 groups
        int l_in = g / 6, cg = g % 6, e0 = cg * 8;
        int xi = l_in & 63, vr0 = l_in >> 6;
        bf16x8 yp = load8(ybase_in + (size_t)l_in * 768 + e0);
        float o[8];
        #pragma unroll
        for (int j = 0; j < 8; ++j) o[j] = b2f(yp[j]) + cb[e0 + j];
        #pragma unroll
        for (int dy = 0; dy < 3; ++dy) {
            #pragma unroll
            for (int dx = 0; dx < 3; ++dx) {
                int xx = xi + dx - 1;
                if (xx < 0 || xx > 63) continue;
                bf16x8 vv = *(const bf16x8*)&vs[vr0 + dy][xx][e0];
                const float* cwp = &cwT[dy * 3 + dx][e0];
                #pragma unroll
                for (int j = 0; j < 8; ++j) o[j] += b2f(vv[j]) * cwp[j];
            }
        }
        __hip_bfloat16 ob[8];
        #pragma unroll
        for (int j = 0; j < 8; ++j) ob[j] = __float2bfloat16(o[j]);
        uint4 pk; __builtin_memcpy(&pk, ob, 16);
        *(uint4*)(ybase + (size_t)l_in * 384 + e0) = pk;
    }
}

// ---------------------------------------------------------------------------
// Generic GEMM (kept for proj): C[M,N] = A @ Bw^T + bias.
// ---------------------------------------------------------------------------
template <typename TO, int KC>
__global__ __launch_bounds__(256) void gemm_bf16_nt(
    const __hip_bfloat16* __restrict__ A,
    const __hip_bfloat16* __restrict__ Bw,
    const float* __restrict__ bias,
    TO* __restrict__ C,
    int N, int NXT)
{
    __shared__ __hip_bfloat16 As[128 * 64];
    __shared__ __hip_bfloat16 Bs[64 * 64];
    const int t = threadIdx.x;
    const int w = t >> 6, lane = t & 63;
    const int r16 = lane & 15, quad = lane >> 4;
    const int bx  = blockIdx.x;
    const int xcd = bx & 7, seq = bx >> 3;
    const int n_t = seq % NXT, m_t = seq / NXT;
    const int m0 = (xcd + 8 * m_t) * 128;
    const int n0 = n_t * 64;
    const int wm = w >> 1, wn = w & 1;

    f32x4 acc[4][2];
    #pragma unroll
    for (int mi = 0; mi < 4; ++mi)
        #pragma unroll
        for (int ni = 0; ni < 2; ++ni)
            acc[mi][ni] = (f32x4){0.f, 0.f, 0.f, 0.f};

    for (int k0 = 0; k0 < KC; k0 += 64) {
        #pragma unroll
        for (int p = 0; p < 4; ++p) {
            int c = p * 64 + lane;
            int rl = c >> 3;
            int cc = (c & 7) ^ (rl & 7);
            gl_lds16(A + (size_t)(m0 + w * 32 + rl) * KC + k0 + cc * 8,
                     &As[(w * 256 + c) * 8]);
        }
        #pragma unroll
        for (int p = 0; p < 2; ++p) {
            int c = p * 64 + lane;
            int rl = c >> 3;
            int cc = (c & 7) ^ (rl & 7);
            gl_lds16(Bw + (size_t)(n0 + w * 16 + rl) * KC + k0 + cc * 8,
                     &Bs[(w * 128 + c) * 8]);
        }
        __syncthreads();
        bf16x8 af[4][2], bfr[2][2];
        #pragma unroll
        for (int ks = 0; ks < 2; ++ks) {
            #pragma unroll
            for (int mi = 0; mi < 4; ++mi) {
                int row = wm * 64 + mi * 16 + r16;
                int pc  = (ks * 4 + quad) ^ (r16 & 7);
                af[mi][ks] = *(const bf16x8*)&As[row * 64 + pc * 8];
            }
            #pragma unroll
            for (int ni = 0; ni < 2; ++ni) {
                int row = wn * 32 + ni * 16 + r16;
                int pc  = (ks * 4 + quad) ^ (r16 & 7);
                bfr[ni][ks] = *(const bf16x8*)&Bs[row * 64 + pc * 8];
            }
        }
        #pragma unroll
        for (int ks = 0; ks < 2; ++ks)
            #pragma unroll
            for (int mi = 0; mi < 4; ++mi)
                #pragma unroll
                for (int ni = 0; ni < 2; ++ni)
                    acc[mi][ni] = __builtin_amdgcn_mfma_f32_16x16x32_bf16(
                        af[mi][ks], bfr[ni][ks], acc[mi][ni], 0, 0, 0);
        __syncthreads();
    }

    #pragma unroll
    for (int ni = 0; ni < 2; ++ni) {
        int col = n0 + wn * 32 + ni * 16 + r16;
        float bv = bias[col];
        #pragma unroll
        for (int mi = 0; mi < 4; ++mi)
            #pragma unroll
            for (int reg = 0; reg < 4; ++reg) {
                int row = m0 + wm * 64 + mi * 16 + quad * 4 + reg;
                storef(&C[(size_t)row * N + col], acc[mi][ni][reg] + bv);
            }
    }
}

// ---------------------------------------------------------------------------
extern "C" void kernel_launch(void* const* d_in, const int* in_sizes, int n_in,
                              void* d_out, int out_size, void* d_ws, size_t ws_size,
                              hipStream_t stream)
{
    const float* x      = (const float*)d_in[0];
    const float* qkv_w  = (const float*)d_in[1];
    const float* qkv_b  = (const float*)d_in[2];
    const float* proj_w = (const float*)d_in[3];
    const float* proj_b = (const float*)d_in[4];
    const float* temp   = (const float*)d_in[5];
    const float* conv_w = (const float*)d_in[6];
    const float* conv_b = (const float*)d_in[7];

    char* ws = (char*)d_ws;
    // layout (R10 fix: S2 = 4,718,592 B; m/weights moved past it):
    __hip_bfloat16* vy   = (__hip_bfloat16*)(ws);                 // 0 .. 50,331,648
    __hip_bfloat16* xT   = (__hip_bfloat16*)(ws);                 // alias (dead before vy)
    __hip_bfloat16* xb   = (__hip_bfloat16*)(ws + 50331648);      // .. 75,497,472
    __hip_bfloat16* yb   = (__hip_bfloat16*)(ws + 50331648);      // alias (after xb dead)
    float* Spart         = (float*)(ws + 75497472);               // .. 94,371,840
    float* T             = (float*)(ws + 75497472);               // 9,437,184 (over dead Spart)
    __hip_bfloat16* weff = (__hip_bfloat16*)(ws + 84934656);      // .. 87,293,952 (over dead Spart)
    float* beff          = (float*)(ws + 87293952);               // .. 87,306,240 (over dead Spart)
    __hip_bfloat16* S2   = (__hip_bfloat16*)(ws + 94371840);      // .. 99,090,432 (4,718,592 B)
    float* m             = (float*)(ws + 99090432);               // .. 99,102,720
    __hip_bfloat16* qkv_wb  = (__hip_bfloat16*)(ws + 99102720);   // .. 99,987,456
    __hip_bfloat16* proj_wb = (__hip_bfloat16*)(ws + 99987456);   // .. 100,282,368

    float* out      = (float*)d_out;
    float* attn_out = out + 12582912;

    // 0) convert x + weights to bf16; zero m
    cvt_kernel<<<6435, 256, 0, stream>>>(x, xb, qkv_w, qkv_wb, proj_w, proj_wb,
                                         (uint4*)m);
    // 1) xT = X^T per batch; m = X^T 1
    xpose_kernel<<<dim3(64, 6, 8), 256, 0, stream>>>(xb, xT, m);
    // 2) S partials = X^T X (split-K, plain stores)
    syrk_part<<<576, 256, 0, stream>>>(xT, Spart);
    // 3) sum partials -> S hi/lo bf16
    cvtS_kernel<<<576, 256, 0, stream>>>(Spart, S2);
    // 4) T = [Wq;Wk] S (fp32-precision via hi+lo passes)
    gemm_T<<<288, 256, 0, stream>>>(qkv_wb, S2, T);
    // 5) per-head: G, invnorms, attn_out, A2, W_eff, b_eff
    head_kernel<<<64, 256, 0, stream>>>(T, m, qkv_wb, qkv_b, temp,
                                        attn_out, weff, beff);
    // 6) vy = [ v | y_pre ] = X @ [Wv | W_eff]^T + bias
    gemm_vy<<<3072, 256, 0, stream>>>(xb, qkv_wb, weff, qkv_b, beff, vy);
    // 7) yb = y_pre + lepe(v)   (overwrites xb alias)
    lepe_kernel<<<dim3(32, 64), 256, 0, stream>>>(vy, conv_w, conv_b, yb);
    // 8) out = yb @ proj_w^T + proj_b
    gemm_bf16_nt<float, 384><<<1536, 256, 0, stream>>>(
        yb, proj_wb, proj_b, out, 384, 6);
}

// Round 12
// 273.097 us; speedup vs baseline: 1.5217x; 1.5217x over previous
//
#include <hip/hip_runtime.h>
#include <hip/hip_bf16.h>

// B=8, L=4096, C=384, h=8, d=48, H=W=64
// Algebraic restructure: G = k^T v = Wk (X^T X) Wv^T (+bias terms); y = q@A2
// = X (Wq^T A2) -> per-batch folded weight. q,k never materialized at length L.
// S kept to fp32 precision via bf16 hi+lo split; Tk likewise (hi/lo) for the
// MFMA G GEMM. R11 head_kernel (194us, 32-way LDS conflicts, grid 64 scalar)
// split into head1 (scalar smalls) + gemm_G (MFMA) + gemm_weff (parallel VALU).

typedef __bf16 bf16x8 __attribute__((ext_vector_type(8)));
typedef float f32x4 __attribute__((ext_vector_type(4)));

__device__ inline __bf16 f2b(float f) {
    __hip_bfloat16 h = __float2bfloat16(f);
    __bf16 r; __builtin_memcpy(&r, &h, 2); return r;
}
__device__ inline float b2f(__hip_bfloat16 h) { return __bfloat162float(h); }
__device__ inline float b2f(__bf16 v) {
    __hip_bfloat16 h; __builtin_memcpy(&h, &v, 2); return __bfloat162float(h);
}

__device__ inline bf16x8 load8(const __hip_bfloat16* p) {
    uint4 v = *(const uint4*)p;
    bf16x8 r; __builtin_memcpy(&r, &v, 16); return r;
}
__device__ inline bf16x8 load8(const float* p) {
    float4 a = *(const float4*)p;
    float4 b = *(const float4*)(p + 4);
    bf16x8 r;
    r[0] = f2b(a.x); r[1] = f2b(a.y); r[2] = f2b(a.z); r[3] = f2b(a.w);
    r[4] = f2b(b.x); r[5] = f2b(b.y); r[6] = f2b(b.z); r[7] = f2b(b.w);
    return r;
}

__device__ inline void storef(float* p, float v) { *p = v; }
__device__ inline void storef(__hip_bfloat16* p, float v) { *p = __float2bfloat16(v); }

// async 16B global -> LDS (wave-uniform base + lane*16 dest required)
__device__ inline void gl_lds16(const __hip_bfloat16* g, __hip_bfloat16* l) {
    __builtin_amdgcn_global_load_lds(
        (const __attribute__((address_space(1))) void*)g,
        (__attribute__((address_space(3))) void*)l,
        16, 0, 0);
}

// ---------------------------------------------------------------------------
// fp32 -> bf16: x (6144 blocks), qkv_w (216), proj_w (72); blocks >= 6432
// zero the m accumulator (768 uint4 = 3 blocks).
// ---------------------------------------------------------------------------
__global__ __launch_bounds__(256) void cvt_kernel(
    const float* __restrict__ x,  __hip_bfloat16* __restrict__ xb,
    const float* __restrict__ qw, __hip_bfloat16* __restrict__ qwb,
    const float* __restrict__ pw, __hip_bfloat16* __restrict__ pwb,
    uint4* __restrict__ zdst)
{
    int blk = blockIdx.x;
    if (blk >= 6432) {
        zdst[(size_t)(blk - 6432) * 256 + threadIdx.x] = (uint4){0, 0, 0, 0};
        return;
    }
    const float* src; __hip_bfloat16* dst; int base;
    if (blk < 6144)      { src = x;  dst = xb;  base = blk; }
    else if (blk < 6360) { src = qw; dst = qwb; base = blk - 6144; }
    else                 { src = pw; dst = pwb; base = blk - 6360; }
    int i = base * 256 + threadIdx.x;
    bf16x8 v = load8(src + (size_t)i * 8);
    *(bf16x8*)(dst + (size_t)i * 8) = v;
}

// ---------------------------------------------------------------------------
// Transpose X (bf16 [B,4096,384]) -> xT (bf16 [B,384,4096]); also m = X^T 1.
// ---------------------------------------------------------------------------
__global__ __launch_bounds__(256) void xpose_kernel(
    const __hip_bfloat16* __restrict__ xb, __hip_bfloat16* __restrict__ xT,
    float* __restrict__ m)
{
    __shared__ __hip_bfloat16 tile[64][72];
    const int lt = blockIdx.x, ct = blockIdx.y, b = blockIdx.z;
    const int l0 = lt * 64, c0 = ct * 64;
    const int t = threadIdx.x;

    #pragma unroll
    for (int p = 0; p < 2; ++p) {
        int cid = t + p * 256;
        int row = cid >> 3, ch = cid & 7;
        *(bf16x8*)&tile[row][ch * 8] =
            load8(xb + (size_t)(b * 4096 + l0 + row) * 384 + c0 + ch * 8);
    }
    __syncthreads();

    #pragma unroll
    for (int p = 0; p < 2; ++p) {
        int ocid = t + p * 256;
        int c = ocid >> 3, lch = ocid & 7;
        __hip_bfloat16 vals[8];
        #pragma unroll
        for (int k = 0; k < 8; ++k) {
            int j = (k + lch) & 7;
            vals[j] = tile[lch * 8 + j][c];
        }
        bf16x8 pk;
        float s = 0.f;
        #pragma unroll
        for (int j = 0; j < 8; ++j) { pk[j] = *(__bf16*)&vals[j]; s += b2f(vals[j]); }
        *(bf16x8*)(xT + ((size_t)b * 384 + c0 + c) * 4096 + l0 + lch * 8) = pk;
        s += __shfl_xor(s, 1); s += __shfl_xor(s, 2); s += __shfl_xor(s, 4);
        if ((ocid & 7) == 0) atomicAdd(&m[b * 384 + c0 + c], s);
    }
}

// ---------------------------------------------------------------------------
// S partials: Spart[split][b][384][384] = X^T X over l-quarter (plain stores).
// ---------------------------------------------------------------------------
__global__ __launch_bounds__(256) void syrk_part(
    const __hip_bfloat16* __restrict__ xT, float* __restrict__ Spart)
{
    __shared__ __hip_bfloat16 As[128 * 64];
    __shared__ __hip_bfloat16 Bs[64 * 64];
    const int t = threadIdx.x;
    const int w = t >> 6, lane = t & 63;
    const int r16 = lane & 15, quad = lane >> 4;
    const int bx = blockIdx.x;
    const int b = bx / 72, rem = bx % 72;
    const int tile = rem / 4, split = rem % 4;
    const int m0 = (tile / 6) * 128, n0 = (tile % 6) * 64;
    const int k_lo = split * 1024;
    const int wm = w >> 1, wn = w & 1;
    const __hip_bfloat16* A = xT + (size_t)b * 384 * 4096;

    f32x4 acc[4][2];
    #pragma unroll
    for (int mi = 0; mi < 4; ++mi)
        #pragma unroll
        for (int ni = 0; ni < 2; ++ni)
            acc[mi][ni] = (f32x4){0.f, 0.f, 0.f, 0.f};

    for (int it = 0; it < 16; ++it) {
        const int k0 = k_lo + it * 64;
        #pragma unroll
        for (int p = 0; p < 4; ++p) {
            int c = p * 64 + lane;
            int rl = c >> 3;
            int cc = (c & 7) ^ (rl & 7);
            gl_lds16(A + (size_t)(m0 + w * 32 + rl) * 4096 + k0 + cc * 8,
                     &As[(w * 256 + c) * 8]);
        }
        #pragma unroll
        for (int p = 0; p < 2; ++p) {
            int c = p * 64 + lane;
            int rl = c >> 3;
            int cc = (c & 7) ^ (rl & 7);
            gl_lds16(A + (size_t)(n0 + w * 16 + rl) * 4096 + k0 + cc * 8,
                     &Bs[(w * 128 + c) * 8]);
        }
        __syncthreads();
        bf16x8 af[4][2], bfr[2][2];
        #pragma unroll
        for (int ks = 0; ks < 2; ++ks) {
            #pragma unroll
            for (int mi = 0; mi < 4; ++mi) {
                int row = wm * 64 + mi * 16 + r16;
                int pc  = (ks * 4 + quad) ^ (r16 & 7);
                af[mi][ks] = *(const bf16x8*)&As[row * 64 + pc * 8];
            }
            #pragma unroll
            for (int ni = 0; ni < 2; ++ni) {
                int row = wn * 32 + ni * 16 + r16;
                int pc  = (ks * 4 + quad) ^ (r16 & 7);
                bfr[ni][ks] = *(const bf16x8*)&Bs[row * 64 + pc * 8];
            }
        }
        #pragma unroll
        for (int ks = 0; ks < 2; ++ks)
            #pragma unroll
            for (int mi = 0; mi < 4; ++mi)
                #pragma unroll
                for (int ni = 0; ni < 2; ++ni)
                    acc[mi][ni] = __builtin_amdgcn_mfma_f32_16x16x32_bf16(
                        af[mi][ks], bfr[ni][ks], acc[mi][ni], 0, 0, 0);
        __syncthreads();
    }

    float* outp = Spart + (size_t)(split * 8 + b) * 147456;
    #pragma unroll
    for (int ni = 0; ni < 2; ++ni) {
        int col = n0 + wn * 32 + ni * 16 + r16;
        #pragma unroll
        for (int mi = 0; mi < 4; ++mi)
            #pragma unroll
            for (int reg = 0; reg < 4; ++reg) {
                int row = m0 + wm * 64 + mi * 16 + quad * 4 + reg;
                outp[(size_t)row * 384 + col] = acc[mi][ni][reg];
            }
    }
}

// ---------------------------------------------------------------------------
// Sum the 4 split partials -> S (fp32), emit bf16 hi/lo pair S2[b][2][384*384].
// ---------------------------------------------------------------------------
__global__ __launch_bounds__(256) void cvtS_kernel(
    const float* __restrict__ Spart, __hip_bfloat16* __restrict__ S2)
{
    size_t base = ((size_t)blockIdx.x * 256 + threadIdx.x) * 8;
    int b = (int)(base / 147456);
    size_t off = base % 147456;
    float s[8];
    #pragma unroll
    for (int j = 0; j < 8; ++j) s[j] = 0.f;
    #pragma unroll
    for (int sp = 0; sp < 4; ++sp) {
        const float* p = Spart + (size_t)(sp * 8 + b) * 147456 + off;
        float4 a = *(const float4*)p, c = *(const float4*)(p + 4);
        s[0] += a.x; s[1] += a.y; s[2] += a.z; s[3] += a.w;
        s[4] += c.x; s[5] += c.y; s[6] += c.z; s[7] += c.w;
    }
    bf16x8 hi, lo;
    #pragma unroll
    for (int j = 0; j < 8; ++j) {
        __hip_bfloat16 h = __float2bfloat16(s[j]);
        hi[j] = *(__bf16*)&h;
        __hip_bfloat16 l2 = __float2bfloat16(s[j] - __bfloat162float(h));
        lo[j] = *(__bf16*)&l2;
    }
    *(bf16x8*)(S2 + (size_t)(b * 2 + 0) * 147456 + off) = hi;
    *(bf16x8*)(S2 + (size_t)(b * 2 + 1) * 147456 + off) = lo;
}

// ---------------------------------------------------------------------------
// T[b] = Wqk (768x384) @ S[b] : two bf16 passes (S_hi, S_lo) -> fp32 T.
// Epilogue also emits Tk2 = hi/lo bf16 of the k-half (rows 384..767) for the
// MFMA G GEMM.
// ---------------------------------------------------------------------------
__global__ __launch_bounds__(256) void gemm_T(
    const __hip_bfloat16* __restrict__ Wqk, const __hip_bfloat16* __restrict__ S2,
    float* __restrict__ T, __hip_bfloat16* __restrict__ Tk2)
{
    __shared__ __hip_bfloat16 As[128 * 64];
    __shared__ __hip_bfloat16 Bs[64 * 64];
    const int t = threadIdx.x;
    const int w = t >> 6, lane = t & 63;
    const int r16 = lane & 15, quad = lane >> 4;
    const int bx = blockIdx.x;
    const int b = bx / 36, rem = bx % 36;
    const int m0 = (rem / 6) * 128, n0 = (rem % 6) * 64;
    const int wm = w >> 1, wn = w & 1;

    f32x4 acc[4][2];
    #pragma unroll
    for (int mi = 0; mi < 4; ++mi)
        #pragma unroll
        for (int ni = 0; ni < 2; ++ni)
            acc[mi][ni] = (f32x4){0.f, 0.f, 0.f, 0.f};

    for (int pass = 0; pass < 2; ++pass) {
        const __hip_bfloat16* Bw = S2 + (size_t)(b * 2 + pass) * 147456;
        for (int k0 = 0; k0 < 384; k0 += 64) {
            #pragma unroll
            for (int p = 0; p < 4; ++p) {
                int c = p * 64 + lane;
                int rl = c >> 3;
                int cc = (c & 7) ^ (rl & 7);
                gl_lds16(Wqk + (size_t)(m0 + w * 32 + rl) * 384 + k0 + cc * 8,
                         &As[(w * 256 + c) * 8]);
            }
            #pragma unroll
            for (int p = 0; p < 2; ++p) {
                int c = p * 64 + lane;
                int rl = c >> 3;
                int cc = (c & 7) ^ (rl & 7);
                gl_lds16(Bw + (size_t)(n0 + w * 16 + rl) * 384 + k0 + cc * 8,
                         &Bs[(w * 128 + c) * 8]);
            }
            __syncthreads();
            bf16x8 af[4][2], bfr[2][2];
            #pragma unroll
            for (int ks = 0; ks < 2; ++ks) {
                #pragma unroll
                for (int mi = 0; mi < 4; ++mi) {
                    int row = wm * 64 + mi * 16 + r16;
                    int pc  = (ks * 4 + quad) ^ (r16 & 7);
                    af[mi][ks] = *(const bf16x8*)&As[row * 64 + pc * 8];
                }
                #pragma unroll
                for (int ni = 0; ni < 2; ++ni) {
                    int row = wn * 32 + ni * 16 + r16;
                    int pc  = (ks * 4 + quad) ^ (r16 & 7);
                    bfr[ni][ks] = *(const bf16x8*)&Bs[row * 64 + pc * 8];
                }
            }
            #pragma unroll
            for (int ks = 0; ks < 2; ++ks)
                #pragma unroll
                for (int mi = 0; mi < 4; ++mi)
                    #pragma unroll
                    for (int ni = 0; ni < 2; ++ni)
                        acc[mi][ni] = __builtin_amdgcn_mfma_f32_16x16x32_bf16(
                            af[mi][ks], bfr[ni][ks], acc[mi][ni], 0, 0, 0);
            __syncthreads();
        }
    }

    float* Cp = T + (size_t)b * 768 * 384;
    #pragma unroll
    for (int ni = 0; ni < 2; ++ni) {
        int col = n0 + wn * 32 + ni * 16 + r16;
        #pragma unroll
        for (int mi = 0; mi < 4; ++mi)
            #pragma unroll
            for (int reg = 0; reg < 4; ++reg) {
                int row = m0 + wm * 64 + mi * 16 + quad * 4 + reg;
                float v = acc[mi][ni][reg];
                Cp[(size_t)row * 384 + col] = v;
                if (row >= 384) {   // k-half -> hi/lo bf16 for gemm_G
                    __hip_bfloat16 hv = __float2bfloat16(v);
                    float lov = v - __bfloat162float(hv);
                    size_t o = (size_t)(row - 384) * 384 + col;
                    Tk2[(size_t)(b * 2 + 0) * 147456 + o] = hv;
                    Tk2[(size_t)(b * 2 + 1) * 147456 + o] = __float2bfloat16(lov);
                }
            }
    }
}

// ---------------------------------------------------------------------------
// head1 (grid 64): scalar smalls only, no LDS conflicts.
// aux[bh][4][48] = { ink, inq, kbm, vbm }.
// ---------------------------------------------------------------------------
__global__ __launch_bounds__(256) void head1_kernel(
    const float* __restrict__ T, const float* __restrict__ m,
    const __hip_bfloat16* __restrict__ qkvw, const float* __restrict__ qkv_b,
    float* __restrict__ aux)
{
    __shared__ float kbm_s[48], qbm_s[48];
    const int bh = blockIdx.x; const int b = bh >> 3, h = bh & 7;
    const int t = threadIdx.x;
    const float* mb = m + b * 384;

    if (t < 144) {   // m-dots: kind 0=k,1=v,2=q
        int kind = t / 48, d = t % 48;
        int rbase = (kind == 0) ? 384 + h * 48 + d : (kind == 1) ? 768 + h * 48 + d : h * 48 + d;
        const __hip_bfloat16* wr = qkvw + (size_t)rbase * 384;
        float s = 0.f;
        for (int j0 = 0; j0 < 384; j0 += 8) {
            bf16x8 wv = load8(wr + j0);
            const float4 a = *(const float4*)(mb + j0);
            const float4 c = *(const float4*)(mb + j0 + 4);
            s += b2f(wv[0])*a.x + b2f(wv[1])*a.y + b2f(wv[2])*a.z + b2f(wv[3])*a.w
               + b2f(wv[4])*c.x + b2f(wv[5])*c.y + b2f(wv[6])*c.z + b2f(wv[7])*c.w;
        }
        if (kind == 0) { kbm_s[d] = s; aux[(size_t)bh * 192 + 96 + d] = s; }
        else if (kind == 1) { aux[(size_t)bh * 192 + 144 + d] = s; }
        else qbm_s[d] = s;
    }
    __syncthreads();

    if (t < 96) {   // sumsq -> invnorms
        int d = t % 48; bool isq = t >= 48;
        const float* trow = T + ((size_t)b * 768 + (isq ? 0 : 384) + h * 48 + d) * 384;
        const __hip_bfloat16* wr = qkvw + (size_t)((isq ? 0 : 384) + h * 48 + d) * 384;
        float bb = qkv_b[(isq ? 0 : 384) + h * 48 + d];
        float s = 0.f;
        for (int j0 = 0; j0 < 384; j0 += 8) {
            bf16x8 wv = load8(wr + j0);
            const float4 a = *(const float4*)(trow + j0);
            const float4 c = *(const float4*)(trow + j0 + 4);
            s += a.x*b2f(wv[0]) + a.y*b2f(wv[1]) + a.z*b2f(wv[2]) + a.w*b2f(wv[3])
               + c.x*b2f(wv[4]) + c.y*b2f(wv[5]) + c.z*b2f(wv[6]) + c.w*b2f(wv[7]);
        }
        s += 2.f * bb * (isq ? qbm_s[d] : kbm_s[d]) + 4096.f * bb * bb;
        float r = 1.f / fmaxf(sqrtf(s), 1e-12f);
        aux[(size_t)bh * 192 + (isq ? 48 : 0) + d] = r;
    }
}

// ---------------------------------------------------------------------------
// gemm_G (grid 64, MFMA): G_h = Tk_h(hi/lo) @ Wv_h^T, fragments direct from
// global (L2-hot, no LDS staging). 4 waves on K-quarters; overlay reduce;
// all-256-thread merge applies rank-1 bias terms -> attn_out + A2 (fp32).
// ---------------------------------------------------------------------------
__global__ __launch_bounds__(256) void gemm_G(
    const __hip_bfloat16* __restrict__ Tk2, const __hip_bfloat16* __restrict__ qkvw,
    const float* __restrict__ aux, const float* __restrict__ qkv_b,
    const float* __restrict__ temp,
    float* __restrict__ attn_out, float* __restrict__ A2)
{
    __shared__ __attribute__((aligned(16))) float red[4][48][49];   // 37632 B

    const int bh = blockIdx.x; const int b = bh >> 3, h = bh & 7;
    const int t = threadIdx.x;
    const int w = t >> 6, lane = t & 63;
    const int r16 = lane & 15, quad = lane >> 4;
    const float tf = temp[h];

    f32x4 acc[3][3];
    #pragma unroll
    for (int mi = 0; mi < 3; ++mi)
        #pragma unroll
        for (int ni = 0; ni < 3; ++ni)
            acc[mi][ni] = (f32x4){0.f, 0.f, 0.f, 0.f};

    const __hip_bfloat16* Wv = qkvw + (size_t)(768 + h * 48) * 384;
    #pragma unroll
    for (int pass = 0; pass < 2; ++pass) {
        const __hip_bfloat16* Ab = Tk2 + (size_t)(b * 2 + pass) * 147456 + (size_t)(h * 48) * 384;
        #pragma unroll
        for (int ks = 0; ks < 3; ++ks) {
            int k0 = w * 96 + ks * 32;
            bf16x8 af[3], bfr[3];
            #pragma unroll
            for (int mi = 0; mi < 3; ++mi)
                af[mi] = load8(Ab + (size_t)(mi * 16 + r16) * 384 + k0 + quad * 8);
            #pragma unroll
            for (int ni = 0; ni < 3; ++ni)
                bfr[ni] = load8(Wv + (size_t)(ni * 16 + r16) * 384 + k0 + quad * 8);
            #pragma unroll
            for (int mi = 0; mi < 3; ++mi)
                #pragma unroll
                for (int ni = 0; ni < 3; ++ni)
                    acc[mi][ni] = __builtin_amdgcn_mfma_f32_16x16x32_bf16(
                        af[mi], bfr[ni], acc[mi][ni], 0, 0, 0);
        }
    }

    // partials to LDS (plain writes, padded rows)
    #pragma unroll
    for (int mi = 0; mi < 3; ++mi)
        #pragma unroll
        for (int ni = 0; ni < 3; ++ni)
            #pragma unroll
            for (int reg = 0; reg < 4; ++reg)
                red[w][mi * 16 + quad * 4 + reg][ni * 16 + r16] = acc[mi][ni][reg];
    __syncthreads();

    const float* auxb = aux + (size_t)bh * 192;
    for (int cell = t; cell < 2304; cell += 256) {
        int d = cell / 48, e = cell % 48;
        float g = red[0][d][e] + red[1][d][e] + red[2][d][e] + red[3][d][e];
        float bk = qkv_b[384 + h * 48 + d];
        float bv = qkv_b[768 + h * 48 + e];
        g += auxb[96 + d] * bv + bk * auxb[144 + e] + 4096.f * bk * bv;
        float av = g * auxb[d] * tf;          // * ink[d]
        attn_out[(size_t)bh * 2304 + cell] = av;
        A2[(size_t)bh * 2304 + cell] = av * auxb[48 + d];   // * inq[d]
    }
}

// ---------------------------------------------------------------------------
// gemm_weff (grid (6, 64)): weff[e][i] = sum_d A2[d][e] Wq_h[d][i], bf16 out.
// A2s reads wave-broadcast; wlq reads consecutive-bank (conflict-free).
// Also beff (ci==0).
// ---------------------------------------------------------------------------
__global__ __launch_bounds__(256) void gemm_weff(
    const float* __restrict__ A2, const __hip_bfloat16* __restrict__ qkvw,
    const float* __restrict__ qkv_b,
    __hip_bfloat16* __restrict__ weff, float* __restrict__ beff)
{
    __shared__ __attribute__((aligned(16))) float A2s[2304];        // [d][e]
    __shared__ __hip_bfloat16 wlq[48][64];

    const int ci = blockIdx.x, bh = blockIdx.y;
    const int b = bh >> 3, h = bh & 7;
    const int t = threadIdx.x;

    for (int i = t; i < 576; i += 256)
        *(float4*)&A2s[i * 4] = *(const float4*)(A2 + (size_t)bh * 2304 + i * 4);
    for (int i = t; i < 384; i += 256) {
        int r = i / 8, ch = i % 8;
        *(bf16x8*)&wlq[r][ch * 8] = load8(qkvw + (size_t)(h * 48 + r) * 384 + ci * 64 + ch * 8);
    }
    __syncthreads();

    const int i2 = t & 63, eg = t >> 6;
    float s[12];
    #pragma unroll
    for (int j = 0; j < 12; ++j) s[j] = 0.f;
    for (int d = 0; d < 48; ++d) {
        float wv = b2f(wlq[d][i2]);
        #pragma unroll
        for (int j = 0; j < 12; ++j)
            s[j] += A2s[d * 48 + eg * 12 + j] * wv;
    }
    #pragma unroll
    for (int j = 0; j < 12; ++j) {
        int e = eg * 12 + j;
        weff[((size_t)b * 384 + h * 48 + e) * 384 + ci * 64 + i2] = __float2bfloat16(s[j]);
    }
    if (ci == 0 && t < 48) {
        float sb = 0.f;
        #pragma unroll
        for (int d = 0; d < 48; ++d) sb += qkv_b[h * 48 + d] * A2s[d * 48 + t];
        beff[(size_t)b * 384 + h * 48 + t] = sb;
    }
}

// ---------------------------------------------------------------------------
// vy GEMM: C[32768][768] = [ v | y_pre ]. bf16 out. Grid 3072, XCD swizzle.
// ---------------------------------------------------------------------------
__global__ __launch_bounds__(256) void gemm_vy(
    const __hip_bfloat16* __restrict__ A, const __hip_bfloat16* __restrict__ qkvw,
    const __hip_bfloat16* __restrict__ weff,
    const float* __restrict__ qkv_b, const float* __restrict__ beff,
    __hip_bfloat16* __restrict__ C)
{
    __shared__ __hip_bfloat16 As[128 * 64];
    __shared__ __hip_bfloat16 Bs[64 * 64];
    const int t = threadIdx.x;
    const int w = t >> 6, lane = t & 63;
    const int r16 = lane & 15, quad = lane >> 4;
    const int bx = blockIdx.x;
    const int xcd = bx & 7, seq = bx >> 3;
    const int n_t = seq % 12, m_t = seq / 12;
    const int m0 = (xcd + 8 * m_t) * 128;
    const int n0 = n_t * 64;
    const int b = m0 >> 12;
    const int wm = w >> 1, wn = w & 1;

    f32x4 acc[4][2];
    #pragma unroll
    for (int mi = 0; mi < 4; ++mi)
        #pragma unroll
        for (int ni = 0; ni < 2; ++ni)
            acc[mi][ni] = (f32x4){0.f, 0.f, 0.f, 0.f};

    for (int k0 = 0; k0 < 384; k0 += 64) {
        #pragma unroll
        for (int p = 0; p < 4; ++p) {
            int c = p * 64 + lane;
            int rl = c >> 3;
            int cc = (c & 7) ^ (rl & 7);
            gl_lds16(A + (size_t)(m0 + w * 32 + rl) * 384 + k0 + cc * 8,
                     &As[(w * 256 + c) * 8]);
        }
        #pragma unroll
        for (int p = 0; p < 2; ++p) {
            int c = p * 64 + lane;
            int rl = c >> 3;
            int cc = (c & 7) ^ (rl & 7);
            int n = n0 + w * 16 + rl;
            const __hip_bfloat16* brow = (n < 384)
                ? qkvw + (size_t)(768 + n) * 384
                : weff + ((size_t)b * 384 + (n - 384)) * 384;
            gl_lds16(brow + k0 + cc * 8, &Bs[(w * 128 + c) * 8]);
        }
        __syncthreads();
        bf16x8 af[4][2], bfr[2][2];
        #pragma unroll
        for (int ks = 0; ks < 2; ++ks) {
            #pragma unroll
            for (int mi = 0; mi < 4; ++mi) {
                int row = wm * 64 + mi * 16 + r16;
                int pc  = (ks * 4 + quad) ^ (r16 & 7);
                af[mi][ks] = *(const bf16x8*)&As[row * 64 + pc * 8];
            }
            #pragma unroll
            for (int ni = 0; ni < 2; ++ni) {
                int row = wn * 32 + ni * 16 + r16;
                int pc  = (ks * 4 + quad) ^ (r16 & 7);
                bfr[ni][ks] = *(const bf16x8*)&Bs[row * 64 + pc * 8];
            }
        }
        #pragma unroll
        for (int ks = 0; ks < 2; ++ks)
            #pragma unroll
            for (int mi = 0; mi < 4; ++mi)
                #pragma unroll
                for (int ni = 0; ni < 2; ++ni)
                    acc[mi][ni] = __builtin_amdgcn_mfma_f32_16x16x32_bf16(
                        af[mi][ks], bfr[ni][ks], acc[mi][ni], 0, 0, 0);
        __syncthreads();
    }

    #pragma unroll
    for (int ni = 0; ni < 2; ++ni) {
        int col = n0 + wn * 32 + ni * 16 + r16;
        float bv = (col < 384) ? qkv_b[768 + col] : beff[(size_t)b * 384 + col - 384];
        #pragma unroll
        for (int mi = 0; mi < 4; ++mi)
            #pragma unroll
            for (int reg = 0; reg < 4; ++reg) {
                int row = m0 + wm * 64 + mi * 16 + quad * 4 + reg;
                C[(size_t)row * 768 + col] = __float2bfloat16(acc[mi][ni][reg] + bv);
            }
    }
}

// ---------------------------------------------------------------------------
// yb = y_pre + lepe(v): depthwise 3x3 conv on v + bias. Grid (32, 64).
// ---------------------------------------------------------------------------
__global__ __launch_bounds__(256) void lepe_kernel(
    const __hip_bfloat16* __restrict__ vy,
    const float* __restrict__ conv_w, const float* __restrict__ conv_b,
    __hip_bfloat16* __restrict__ y)
{
    __shared__ __hip_bfloat16 vs[4][64][48];
    __shared__ float cwT[9][48];
    __shared__ float cb[48];

    const int bh = blockIdx.y; const int b = bh >> 3; const int h = bh & 7;
    const int yi0 = blockIdx.x * 2;
    const int l0  = yi0 * 64;
    const int t = threadIdx.x;

    const __hip_bfloat16* vbase = vy + (size_t)b * 4096 * 768 + h * 48;
    #pragma unroll
    for (int i = 0; i < 6; ++i) {
        int chunk = t + i * 256;
        int r = chunk / 384, rem = chunk % 384;
        int xx = rem / 6, cg = rem % 6;
        int yy = yi0 - 1 + r;
        bf16x8 v = (yy >= 0 && yy < 64)
            ? load8(vbase + (size_t)(yy * 64 + xx) * 768 + cg * 8)
            : (bf16x8)0;
        *(bf16x8*)&vs[r][xx][cg * 8] = v;
    }
    for (int i = t; i < 432; i += 256)
        cwT[i / 48][i % 48] = conv_w[(h * 48 + (i % 48)) * 9 + (i / 48)];
    if (t < 48) cb[t] = conv_b[h * 48 + t];
    __syncthreads();

    const __hip_bfloat16* ybase_in = vy + (size_t)(b * 4096 + l0) * 768 + 384 + h * 48;
    __hip_bfloat16* ybase = y + (size_t)(b * 4096 + l0) * 384 + h * 48;
    #pragma unroll
    for (int i = 0; i < 3; ++i) {
        int g = t + i * 256;
        int l_in = g / 6, cg = g % 6, e0 = cg * 8;
        int xi = l_in & 63, vr0 = l_in >> 6;
        bf16x8 yp = load8(ybase_in + (size_t)l_in * 768 + e0);
        float o[8];
        #pragma unroll
        for (int j = 0; j < 8; ++j) o[j] = b2f(yp[j]) + cb[e0 + j];
        #pragma unroll
        for (int dy = 0; dy < 3; ++dy) {
            #pragma unroll
            for (int dx = 0; dx < 3; ++dx) {
                int xx = xi + dx - 1;
                if (xx < 0 || xx > 63) continue;
                bf16x8 vv = *(const bf16x8*)&vs[vr0 + dy][xx][e0];
                const float* cwp = &cwT[dy * 3 + dx][e0];
                #pragma unroll
                for (int j = 0; j < 8; ++j) o[j] += b2f(vv[j]) * cwp[j];
            }
        }
        __hip_bfloat16 ob[8];
        #pragma unroll
        for (int j = 0; j < 8; ++j) ob[j] = __float2bfloat16(o[j]);
        uint4 pk; __builtin_memcpy(&pk, ob, 16);
        *(uint4*)(ybase + (size_t)l_in * 384 + e0) = pk;
    }
}

// ---------------------------------------------------------------------------
// Generic GEMM (proj): C[M,N] = A @ Bw^T + bias.
// ---------------------------------------------------------------------------
template <typename TO, int KC>
__global__ __launch_bounds__(256) void gemm_bf16_nt(
    const __hip_bfloat16* __restrict__ A,
    const __hip_bfloat16* __restrict__ Bw,
    const float* __restrict__ bias,
    TO* __restrict__ C,
    int N, int NXT)
{
    __shared__ __hip_bfloat16 As[128 * 64];
    __shared__ __hip_bfloat16 Bs[64 * 64];
    const int t = threadIdx.x;
    const int w = t >> 6, lane = t & 63;
    const int r16 = lane & 15, quad = lane >> 4;
    const int bx  = blockIdx.x;
    const int xcd = bx & 7, seq = bx >> 3;
    const int n_t = seq % NXT, m_t = seq / NXT;
    const int m0 = (xcd + 8 * m_t) * 128;
    const int n0 = n_t * 64;
    const int wm = w >> 1, wn = w & 1;

    f32x4 acc[4][2];
    #pragma unroll
    for (int mi = 0; mi < 4; ++mi)
        #pragma unroll
        for (int ni = 0; ni < 2; ++ni)
            acc[mi][ni] = (f32x4){0.f, 0.f, 0.f, 0.f};

    for (int k0 = 0; k0 < KC; k0 += 64) {
        #pragma unroll
        for (int p = 0; p < 4; ++p) {
            int c = p * 64 + lane;
            int rl = c >> 3;
            int cc = (c & 7) ^ (rl & 7);
            gl_lds16(A + (size_t)(m0 + w * 32 + rl) * KC + k0 + cc * 8,
                     &As[(w * 256 + c) * 8]);
        }
        #pragma unroll
        for (int p = 0; p < 2; ++p) {
            int c = p * 64 + lane;
            int rl = c >> 3;
            int cc = (c & 7) ^ (rl & 7);
            gl_lds16(Bw + (size_t)(n0 + w * 16 + rl) * KC + k0 + cc * 8,
                     &Bs[(w * 128 + c) * 8]);
        }
        __syncthreads();
        bf16x8 af[4][2], bfr[2][2];
        #pragma unroll
        for (int ks = 0; ks < 2; ++ks) {
            #pragma unroll
            for (int mi = 0; mi < 4; ++mi) {
                int row = wm * 64 + mi * 16 + r16;
                int pc  = (ks * 4 + quad) ^ (r16 & 7);
                af[mi][ks] = *(const bf16x8*)&As[row * 64 + pc * 8];
            }
            #pragma unroll
            for (int ni = 0; ni < 2; ++ni) {
                int row = wn * 32 + ni * 16 + r16;
                int pc  = (ks * 4 + quad) ^ (r16 & 7);
                bfr[ni][ks] = *(const bf16x8*)&Bs[row * 64 + pc * 8];
            }
        }
        #pragma unroll
        for (int ks = 0; ks < 2; ++ks)
            #pragma unroll
            for (int mi = 0; mi < 4; ++mi)
                #pragma unroll
                for (int ni = 0; ni < 2; ++ni)
                    acc[mi][ni] = __builtin_amdgcn_mfma_f32_16x16x32_bf16(
                        af[mi][ks], bfr[ni][ks], acc[mi][ni], 0, 0, 0);
        __syncthreads();
    }

    #pragma unroll
    for (int ni = 0; ni < 2; ++ni) {
        int col = n0 + wn * 32 + ni * 16 + r16;
        float bv = bias[col];
        #pragma unroll
        for (int mi = 0; mi < 4; ++mi)
            #pragma unroll
            for (int reg = 0; reg < 4; ++reg) {
                int row = m0 + wm * 64 + mi * 16 + quad * 4 + reg;
                storef(&C[(size_t)row * N + col], acc[mi][ni][reg] + bv);
            }
    }
}

// ---------------------------------------------------------------------------
extern "C" void kernel_launch(void* const* d_in, const int* in_sizes, int n_in,
                              void* d_out, int out_size, void* d_ws, size_t ws_size,
                              hipStream_t stream)
{
    const float* x      = (const float*)d_in[0];
    const float* qkv_w  = (const float*)d_in[1];
    const float* qkv_b  = (const float*)d_in[2];
    const float* proj_w = (const float*)d_in[3];
    const float* proj_b = (const float*)d_in[4];
    const float* temp   = (const float*)d_in[5];
    const float* conv_w = (const float*)d_in[6];
    const float* conv_b = (const float*)d_in[7];

    char* ws = (char*)d_ws;
    __hip_bfloat16* vy   = (__hip_bfloat16*)(ws);                 // 0 .. 50,331,648
    __hip_bfloat16* xT   = (__hip_bfloat16*)(ws);                 // alias (dead before vy)
    __hip_bfloat16* xb   = (__hip_bfloat16*)(ws + 50331648);      // .. 75,497,472
    __hip_bfloat16* yb   = (__hip_bfloat16*)(ws + 50331648);      // alias (after xb dead)
    float* Spart         = (float*)(ws + 75497472);               // .. 94,371,840 (dead after cvtS)
    float* T             = (float*)(ws + 75497472);               // .. 84,934,656
    __hip_bfloat16* Tk2  = (__hip_bfloat16*)(ws + 84934656);      // .. 89,653,248
    __hip_bfloat16* weff = (__hip_bfloat16*)(ws + 89653248);      // .. 92,012,544
    float* beff          = (float*)(ws + 92012544);               // .. 92,024,832
    float* A2            = (float*)(ws + 92024832);               // .. 92,614,656
    float* aux           = (float*)(ws + 92614656);               // .. 92,663,808
    __hip_bfloat16* S2   = (__hip_bfloat16*)(ws + 94371840);      // .. 99,090,432
    float* m             = (float*)(ws + 99090432);               // .. 99,102,720
    __hip_bfloat16* qkv_wb  = (__hip_bfloat16*)(ws + 99102720);   // .. 99,987,456
    __hip_bfloat16* proj_wb = (__hip_bfloat16*)(ws + 99987456);   // .. 100,282,368

    float* out      = (float*)d_out;
    float* attn_out = out + 12582912;

    // 0) convert x + weights to bf16; zero m
    cvt_kernel<<<6435, 256, 0, stream>>>(x, xb, qkv_w, qkv_wb, proj_w, proj_wb,
                                         (uint4*)m);
    // 1) xT = X^T per batch; m = X^T 1
    xpose_kernel<<<dim3(64, 6, 8), 256, 0, stream>>>(xb, xT, m);
    // 2) S partials = X^T X (split-K, plain stores)
    syrk_part<<<576, 256, 0, stream>>>(xT, Spart);
    // 3) sum partials -> S hi/lo bf16
    cvtS_kernel<<<576, 256, 0, stream>>>(Spart, S2);
    // 4) T = [Wq;Wk] S (fp32 via hi+lo passes) + Tk2 hi/lo emit
    gemm_T<<<288, 256, 0, stream>>>(qkv_wb, S2, T, Tk2);
    // 5) per-head scalar smalls -> aux {ink,inq,kbm,vbm}
    head1_kernel<<<64, 256, 0, stream>>>(T, m, qkv_wb, qkv_b, aux);
    // 6) G via MFMA -> attn_out + A2
    gemm_G<<<64, 256, 0, stream>>>(Tk2, qkv_wb, aux, qkv_b, temp, attn_out, A2);
    // 7) W_eff = A2^T-weighted Wq + b_eff
    gemm_weff<<<dim3(6, 64), 256, 0, stream>>>(A2, qkv_wb, qkv_b, weff, beff);
    // 8) vy = [ v | y_pre ] = X @ [Wv | W_eff]^T + bias
    gemm_vy<<<3072, 256, 0, stream>>>(xb, qkv_wb, weff, qkv_b, beff, vy);
    // 9) yb = y_pre + lepe(v)   (overwrites xb alias)
    lepe_kernel<<<dim3(32, 64), 256, 0, stream>>>(vy, conv_w, conv_b, yb);
    // 10) out = yb @ proj_w^T + proj_b
    gemm_bf16_nt<float, 384><<<1536, 256, 0, stream>>>(
        yb, proj_wb, proj_b, out, 384, 6);
}